// Round 1
// baseline (545.589 us; speedup 1.0000x reference)
//
#include <hip/hip_runtime.h>
#include <math.h>

#define NROWS 16384
#define DDIM  2048
#define EEXP  64
#define KD    32      // d-chunk held in VGPRs
#define RPW   8       // rows per wave
#define WAVES 4       // waves per block (block = 256 threads)

__global__ __launch_bounds__(256)
void router_kernel(const float* __restrict__ x,
                   const float* __restrict__ W,
                   const float* __restrict__ b,
                   float* __restrict__ mask_out,
                   float* __restrict__ idx_out) {
    const int lane = threadIdx.x & 63;
    // Force wave id wave-uniform so x addresses become scalar (s_load).
    const int wave = __builtin_amdgcn_readfirstlane((int)(threadIdx.x >> 6));
    const int row0 = blockIdx.x * (RPW * WAVES) + wave * RPW;

    const float* xbase = x + (size_t)row0 * DDIM;   // wave-uniform pointer

    float acc[RPW];
#pragma unroll
    for (int r = 0; r < RPW; ++r) acc[r] = 0.0f;

    for (int d0 = 0; d0 < DDIM; d0 += KD) {
        // W chunk -> VGPRs, lane e holds W[d0+k][e]; coalesced 256B/load,
        // same 8KB chunk shared by all waves on the CU -> L1 hits.
        float w[KD];
#pragma unroll
        for (int k = 0; k < KD; ++k)
            w[k] = W[(d0 + k) * EEXP + lane];

#pragma unroll
        for (int r = 0; r < RPW; ++r) {
            const float* xp = xbase + (size_t)r * DDIM + d0;  // uniform -> s_load
#pragma unroll
            for (int k = 0; k < KD; ++k)
                acc[r] = fmaf(xp[k], w[k], acc[r]);
        }
    }

    const float bias = b[lane];

#pragma unroll 1
    for (int r = 0; r < RPW; ++r) {
        const int row = row0 + r;
        float logit = acc[r] + bias;

        // softmax over the 64 lanes (one expert per lane)
        float m = logit;
#pragma unroll
        for (int off = 32; off >= 1; off >>= 1)
            m = fmaxf(m, __shfl_xor(m, off));
        float ex = __expf(logit - m);
        float s = ex;
#pragma unroll
        for (int off = 32; off >= 1; off >>= 1)
            s += __shfl_xor(s, off);
        float gate = ex / s;

        // top-1 on logits (same order as gates; tie-break lowest index)
        float v1 = logit; int i1 = lane;
#pragma unroll
        for (int off = 32; off >= 1; off >>= 1) {
            float ov = __shfl_xor(v1, off);
            int   oi = __shfl_xor(i1, off);
            if (ov > v1 || (ov == v1 && oi < i1)) { v1 = ov; i1 = oi; }
        }
        // top-2: mask out winner, reduce again
        float v2 = (lane == i1) ? -INFINITY : logit; int i2 = lane;
#pragma unroll
        for (int off = 32; off >= 1; off >>= 1) {
            float ov = __shfl_xor(v2, off);
            int   oi = __shfl_xor(i2, off);
            if (ov > v2 || (ov == v2 && oi < i2)) { v2 = ov; i2 = oi; }
        }

        float outv = (lane == i1 || lane == i2) ? gate : 0.0f;
        mask_out[(size_t)row * EEXP + lane] = outv;   // coalesced 256B store

        if (lane == 0) {
            idx_out[row * 2 + 0] = (float)i1;
            idx_out[row * 2 + 1] = (float)i2;
        }
    }
}

extern "C" void kernel_launch(void* const* d_in, const int* in_sizes, int n_in,
                              void* d_out, int out_size, void* d_ws, size_t ws_size,
                              hipStream_t stream) {
    const float* x = (const float*)d_in[0];
    const float* W = (const float*)d_in[1];
    const float* b = (const float*)d_in[2];
    float* mask_out = (float*)d_out;
    float* idx_out  = mask_out + (size_t)NROWS * EEXP;

    dim3 grid(NROWS / (RPW * WAVES));   // 512 blocks
    dim3 block(256);
    router_kernel<<<grid, block, 0, stream>>>(x, W, b, mask_out, idx_out);
}

// Round 2
// 380.417 us; speedup vs baseline: 1.4342x; 1.4342x over previous
//
#include <hip/hip_runtime.h>
#include <math.h>

#define NROWS 16384
#define DDIM  2048
#define EEXP  64
#define RPW    8              // rows per block (all waves share them)
#define SPLITD 4              // waves per block; each owns DDIM/SPLITD
#define DSLICE (DDIM / SPLITD) // 512
#define KD     8              // W-chunk in registers (double-buffered)

__global__ __launch_bounds__(256, 8)
void router_kernel(const float* __restrict__ x,
                   const float* __restrict__ W,
                   const float* __restrict__ b,
                   float* __restrict__ mask_out,
                   float* __restrict__ idx_out) {
    __shared__ float partial[SPLITD][RPW][EEXP];   // 8 KB

    const int lane = threadIdx.x & 63;
    const int wave = __builtin_amdgcn_readfirstlane((int)(threadIdx.x >> 6));
    const int row0 = blockIdx.x * RPW;
    const int dbase = wave * DSLICE;

    const float* xbase = x + (size_t)row0 * DDIM + dbase;  // wave-uniform -> s_load
    const float* Wp    = W + (size_t)dbase * EEXP + lane;  // coalesced across lanes

    float acc[RPW];
#pragma unroll
    for (int r = 0; r < RPW; ++r) acc[r] = 0.0f;

    // register double-buffer for W: KD loads in flight while FMAing previous KD
    float wc[KD], wn[KD];
#pragma unroll
    for (int k = 0; k < KD; ++k) wc[k] = Wp[k * EEXP];

    for (int d0 = 0; d0 < DSLICE; d0 += KD) {
        const int dn = d0 + KD;
        if (dn < DSLICE) {
#pragma unroll
            for (int k = 0; k < KD; ++k) wn[k] = Wp[(dn + k) * EEXP];
        }
#pragma unroll
        for (int r = 0; r < RPW; ++r) {
            const float* xp = xbase + (size_t)r * DDIM + d0;  // uniform -> s_load
#pragma unroll
            for (int k = 0; k < KD; ++k)
                acc[r] = fmaf(xp[k], wc[k], acc[r]);
        }
#pragma unroll
        for (int k = 0; k < KD; ++k) wc[k] = wn[k];
    }

    // cross-wave (split-D) reduction via LDS
#pragma unroll
    for (int r = 0; r < RPW; ++r) partial[wave][r][lane] = acc[r];
    __syncthreads();

    // each wave finishes RPW/SPLITD = 2 rows
#pragma unroll
    for (int rr = 0; rr < RPW / SPLITD; ++rr) {
        const int r   = wave * (RPW / SPLITD) + rr;
        const int row = row0 + r;

        float logit = partial[0][r][lane] + partial[1][r][lane]
                    + partial[2][r][lane] + partial[3][r][lane] + b[lane];

        // softmax over 64 lanes (one expert per lane)
        float m = logit;
#pragma unroll
        for (int off = 32; off >= 1; off >>= 1)
            m = fmaxf(m, __shfl_xor(m, off));
        float ex = __expf(logit - m);
        float s = ex;
#pragma unroll
        for (int off = 32; off >= 1; off >>= 1)
            s += __shfl_xor(s, off);
        float gate = ex / s;

        // top-1 on logits (tie-break lowest index, matches lax.top_k)
        float v1 = logit; int i1 = lane;
#pragma unroll
        for (int off = 32; off >= 1; off >>= 1) {
            float ov = __shfl_xor(v1, off);
            int   oi = __shfl_xor(i1, off);
            if (ov > v1 || (ov == v1 && oi < i1)) { v1 = ov; i1 = oi; }
        }
        // top-2
        float v2 = (lane == i1) ? -INFINITY : logit; int i2 = lane;
#pragma unroll
        for (int off = 32; off >= 1; off >>= 1) {
            float ov = __shfl_xor(v2, off);
            int   oi = __shfl_xor(i2, off);
            if (ov > v2 || (ov == v2 && oi < i2)) { v2 = ov; i2 = oi; }
        }

        float outv = (lane == i1 || lane == i2) ? gate : 0.0f;
        mask_out[(size_t)row * EEXP + lane] = outv;   // coalesced 256B store

        if (lane == 0) {
            idx_out[row * 2 + 0] = (float)i1;
            idx_out[row * 2 + 1] = (float)i2;
        }
    }
}

extern "C" void kernel_launch(void* const* d_in, const int* in_sizes, int n_in,
                              void* d_out, int out_size, void* d_ws, size_t ws_size,
                              hipStream_t stream) {
    const float* x = (const float*)d_in[0];
    const float* W = (const float*)d_in[1];
    const float* b = (const float*)d_in[2];
    float* mask_out = (float*)d_out;
    float* idx_out  = mask_out + (size_t)NROWS * EEXP;

    dim3 grid(NROWS / RPW);   // 2048 blocks
    dim3 block(256);          // 4 waves, split-D
    router_kernel<<<grid, block, 0, stream>>>(x, W, b, mask_out, idx_out);
}